// Round 20
// baseline (177.771 us; speedup 1.0000x reference)
//
#include <hip/hip_runtime.h>
#include <math.h>

#define D_IN 128
#define D_OUT 64
#define SCALE_PARAM 2.0f
#define NSLOT 64          // spread slots for stats atomics (64B-line spaced)
#define SLOT_STRIDE 16    // floats
#define NPB_LOG 9         // 512 nodes per coarse bucket (pow2)
#define NPB 512
#define MAXBUCK 256       // >= NBUCK = ceil(N/512) = 196
#define MSF_NBLK 512      // multisplit blocks (fused, 256 threads each)
#define PREP_BLKS 16      // prep_w blocks in fused prep+hist kernel

typedef unsigned short ushortt;
typedef __attribute__((ext_vector_type(8))) short bf16x8;
typedef __attribute__((ext_vector_type(4))) float f32x4;

__device__ __forceinline__ ushortt f2bf(float f) {
    union { float f; unsigned u; } cv; cv.f = f;
    unsigned u = cv.u;
    return (ushortt)((u + 0x7FFFu + ((u >> 16) & 1u)) >> 16);
}
__device__ __forceinline__ unsigned cvt_pk_bf16(float a, float b) {
    unsigned r;
    asm("v_cvt_pk_bf16_f32 %0, %1, %2" : "=v"(r) : "v"(a), "v"(b));
    return r;
}
// packed bf16 dot2 with f32 accumulate: d = a.lo*b.lo + a.hi*b.hi + c
__device__ __forceinline__ float dot2bf(unsigned a, unsigned b, float c) {
    float d;
    asm("v_dot2_f32_bf16 %0, %1, %2, %3" : "=v"(d) : "v"(a), "v"(b), "v"(c));
    return d;
}
__device__ __forceinline__ float bflo(unsigned w) {
    union { unsigned u; float f; } cv; cv.u = w << 16;
    return cv.f;
}
__device__ __forceinline__ float bfhi(unsigned w) {
    union { unsigned u; float f; } cv; cv.u = w & 0xFFFF0000u;
    return cv.f;
}

// ---------------- fused: W fragment pre-pack + dst coarse histogram ----
__global__ __launch_bounds__(256) void prep_hist_kernel(
    const float* __restrict__ Wq, const float* __restrict__ Wk,
    const float* __restrict__ Wv, const float* __restrict__ Ws,
    uint4* __restrict__ wfrag,
    const int* __restrict__ dst, int* __restrict__ ccnt, int E)
{
    __shared__ int lc[MAXBUCK];
    const int t = threadIdx.x;
    if (blockIdx.x < PREP_BLKS) {
        const int gid = blockIdx.x * 256 + t;   // 0..4095
        const int l  = gid & 63;
        const int ci = (gid >> 6) & 3;
        const int ks = (gid >> 8) & 3;
        const int m  = (gid >> 10) & 3;
        const float* Wm = (m == 0) ? Wq : (m == 1) ? Wk : (m == 2) ? Wv : Ws;
        const int cl = l & 15;
        const int kb8 = (l >> 4) * 8;
        unsigned pk[4];
#pragma unroll
        for (int p = 0; p < 4; ++p) {
            float f0 = Wm[(ks * 32 + kb8 + 2 * p)     * D_OUT + ci * 16 + cl];
            float f1 = Wm[(ks * 32 + kb8 + 2 * p + 1) * D_OUT + ci * 16 + cl];
            pk[p] = (unsigned)f2bf(f0) | ((unsigned)f2bf(f1) << 16);
        }
        wfrag[gid] = make_uint4(pk[0], pk[1], pk[2], pk[3]);
    } else {
        const int blk = blockIdx.x - PREP_BLKS;       // 0..511
        const int nblk = gridDim.x - PREP_BLKS;       // 512
        if (t < MAXBUCK) lc[t] = 0;
        __syncthreads();
        const int stride = nblk * 256 * 4;
        for (int base = (blk * 256 + t) * 4; base < E; base += stride) {
            if (base + 3 < E) {
                int4 d = *reinterpret_cast<const int4*>(&dst[base]);
                atomicAdd(&lc[d.x >> NPB_LOG], 1);
                atomicAdd(&lc[d.y >> NPB_LOG], 1);
                atomicAdd(&lc[d.z >> NPB_LOG], 1);
                atomicAdd(&lc[d.w >> NPB_LOG], 1);
            } else {
                for (int i = base; i < E; ++i) atomicAdd(&lc[dst[i] >> NPB_LOG], 1);
            }
        }
        __syncthreads();
        if (t < MAXBUCK && lc[t]) atomicAdd(&ccnt[t], lc[t]);
    }
}

// ---------------- coarse scan (tiny) ----------------
__global__ void coarse_scan_kernel(const int* __restrict__ ccnt,
                                   int* __restrict__ bb, int* __restrict__ tails,
                                   int NBUCK)
{
    if (threadIdx.x == 0) {
        int run = 0;
        for (int b = 0; b < NBUCK; ++b) {
            bb[b] = run;
            tails[b] = run;
            run += ccnt[b];
        }
        bb[NBUCK] = run;   // = E
    }
}

// ---------------- fused: multisplit (blocks 0..511) + MFMA GEMM -------
__global__ __launch_bounds__(256) void gemm_ms_kernel(
    const float* __restrict__ x, const uint4* __restrict__ wfrag,
    const float* __restrict__ bq, const float* __restrict__ bk,
    const float* __restrict__ bv, const float* __restrict__ bs,
    ushortt* __restrict__ q, ushortt* __restrict__ kk, ushortt* __restrict__ v,
    float* __restrict__ skip, int N,
    const int* __restrict__ src, const int* __restrict__ dst,
    int* __restrict__ tails, unsigned* __restrict__ ebuf, int E)
{
    __shared__ __align__(16) char smem[64 * 128 * 2];   // 16 KB shared pool
    const int t = threadIdx.x;

    if (blockIdx.x < MSF_NBLK) {
        // ================= multisplit =================
        int* cnt    = (int*)smem;                 // [MAXBUCK]
        int* curc   = (int*)(smem + 1024);        // [MAXBUCK]
        int* base_l = (int*)(smem + 2048);        // [MAXBUCK]
        const int blk = blockIdx.x;
        const int e0 = (int)((long long)blk * E / MSF_NBLK);
        const int e1 = (int)((long long)(blk + 1) * E / MSF_NBLK);
        if (t < MAXBUCK) { cnt[t] = 0; curc[t] = 0; }
        __syncthreads();
        for (int e = e0 + t; e < e1; e += 256)
            atomicAdd(&cnt[dst[e] >> NPB_LOG], 1);
        __syncthreads();
        if (t < MAXBUCK) {
            int c = cnt[t];
            base_l[t] = c ? atomicAdd(&tails[t], c) : 0;
        }
        __syncthreads();
        for (int e = e0 + t; e < e1; e += 256) {
            int d = dst[e];
            int b = d >> NPB_LOG;
            int r = atomicAdd(&curc[b], 1);
            ebuf[base_l[b] + r] = ((unsigned)(d & (NPB - 1)) << 17) | (unsigned)src[e];
        }
        return;
    }

    // ================= GEMM =================
    char* AsB = smem;
    const int w = t >> 6;          // wave id = matrix id
    const int l = t & 63;
    const int cl = l & 15;
    const int kb8 = (l >> 4) * 8;
    const int rbase = (l >> 4) * 4;
    const int row0 = (blockIdx.x - MSF_NBLK) * 64;

    const float* bp = (w == 0) ? bq : (w == 1) ? bk : (w == 2) ? bv : bs;

    // phase 1: issue ALL x loads
    float4 xv[8];
#pragma unroll
    for (int i = 0; i < 8; ++i) {
        int f = i * 256 + t;
        int r = f >> 5;
        int k4 = f & 31;
        int grow = row0 + r;
        xv[i] = make_float4(0.f, 0.f, 0.f, 0.f);
        if (grow < N)
            xv[i] = *reinterpret_cast<const float4*>(&x[(size_t)grow * D_IN + k4 * 4]);
    }

    union U8 { uint4 u; bf16x8 v; };
    bf16x8 bfr[4][4];
#pragma unroll
    for (int ks = 0; ks < 4; ++ks)
#pragma unroll
        for (int ci = 0; ci < 4; ++ci) {
            U8 tmp; tmp.u = wfrag[((w * 4 + ks) * 4 + ci) * 64 + l];
            bfr[ks][ci] = tmp.v;
        }
    float4 bias4[4];
#pragma unroll
    for (int ci = 0; ci < 4; ++ci)
        bias4[ci] = reinterpret_cast<const float4*>(bp)[ci * 4 + (l >> 4)];

    // phase 2: cvt + LDS writes
#pragma unroll
    for (int i = 0; i < 8; ++i) {
        int f = i * 256 + t;
        int r = f >> 5;
        int k4 = f & 31;
        uint2 pk;
        pk.x = cvt_pk_bf16(xv[i].x, xv[i].y);
        pk.y = cvt_pk_bf16(xv[i].z, xv[i].w);
        int addr = r * 256 + ((k4 * 8) ^ ((r & 7) << 4));
        *reinterpret_cast<uint2*>(AsB + addr) = pk;
    }
    __syncthreads();

    f32x4 acc[4][4];
#pragma unroll
    for (int ri = 0; ri < 4; ++ri)
#pragma unroll
        for (int ci = 0; ci < 4; ++ci) acc[ri][ci] = (f32x4)(0.f);

#pragma unroll
    for (int ks = 0; ks < 4; ++ks) {
        bf16x8 afr[4];
#pragma unroll
        for (int ri = 0; ri < 4; ++ri) {
            int row = ri * 16 + cl;
            int kby = ks * 64 + kb8 * 2;
            int addr = row * 256 + (kby ^ ((row & 7) << 4));
            afr[ri] = *reinterpret_cast<const bf16x8*>(AsB + addr);
        }
        // swapped operands -> transposed output fragments
#pragma unroll
        for (int ri = 0; ri < 4; ++ri)
#pragma unroll
            for (int ci = 0; ci < 4; ++ci)
                acc[ri][ci] = __builtin_amdgcn_mfma_f32_16x16x32_bf16(
                    bfr[ks][ci], afr[ri], acc[ri][ci], 0, 0, 0);
    }

    // epilogue: lane holds row=ri*16+cl, cols=ci*16+rbase+0..3
    ushortt* qkv = (w == 0) ? q : (w == 1) ? kk : v;
#pragma unroll
    for (int ri = 0; ri < 4; ++ri) {
        int grow = row0 + ri * 16 + cl;
        if (grow >= N) continue;
        if (w == 3) {
#pragma unroll
            for (int ci = 0; ci < 4; ++ci) {
                float4 o;
                o.x = acc[ri][ci][0] + bias4[ci].x;
                o.y = acc[ri][ci][1] + bias4[ci].y;
                o.z = acc[ri][ci][2] + bias4[ci].z;
                o.w = acc[ri][ci][3] + bias4[ci].w;
                *reinterpret_cast<float4*>(&skip[(size_t)grow * D_OUT + ci * 16 + rbase]) = o;
            }
        } else {
#pragma unroll
            for (int ci = 0; ci < 4; ++ci) {
                uint2 pk;
                pk.x = cvt_pk_bf16(acc[ri][ci][0] + bias4[ci].x,
                                   acc[ri][ci][1] + bias4[ci].y);
                pk.y = cvt_pk_bf16(acc[ri][ci][2] + bias4[ci].z,
                                   acc[ri][ci][3] + bias4[ci].w);
                *reinterpret_cast<uint2*>(&qkv[(size_t)grow * D_OUT + ci * 16 + rbase]) = pk;
            }
        }
    }
}

// ---------------- fine sort within coarse bucket ----------------
__global__ __launch_bounds__(512) void fine_sort_kernel(
    const unsigned* __restrict__ ebuf, const int* __restrict__ bb,
    int* __restrict__ sorted_src, int* __restrict__ row_start,
    int N, int NBUCK)
{
    __shared__ int cnt[NPB];
    __shared__ int cur[NPB];
    __shared__ int wsum[8];
    const int t = threadIdx.x;
    const int b = blockIdx.x;
    const int nbase = b << NPB_LOG;
    const int seg0 = bb[b], seg1 = bb[b + 1];

    cnt[t] = 0; cur[t] = 0;
    __syncthreads();
    for (int j = seg0 + t; j < seg1; j += 512)
        atomicAdd(&cnt[ebuf[j] >> 17], 1);
    __syncthreads();

    {
        const int lane = t & 63, wid = t >> 6;
        int c = cnt[t];
        int x = c;
#pragma unroll
        for (int off = 1; off < 64; off <<= 1) {
            int n = __shfl_up(x, off, 64);
            if (lane >= off) x += n;
        }
        if (lane == 63) wsum[wid] = x;
        __syncthreads();
        int woff = 0;
        for (int w = 0; w < wid; ++w) woff += wsum[w];
        int excl = x - c + woff;
        cnt[t] = excl;
        int node = nbase + t;
        if (node < N) row_start[node] = seg0 + excl;
    }
    if (b == NBUCK - 1 && t == 0) row_start[N] = seg1;
    __syncthreads();

    for (int j = seg0 + t; j < seg1; j += 512) {
        unsigned u = ebuf[j];
        int dl = u >> 17;
        int r = atomicAdd(&cur[dl], 1);
        sorted_src[seg0 + cnt[dl] + r] = (int)(u & 0x1FFFFu);
    }
}

// ---------------- per-node logits + stats: dot2 + 4-deep gather ILP ---
__global__ __launch_bounds__(256) void node_logit_kernel(
    const ushortt* __restrict__ q, const ushortt* __restrict__ k,
    const int* __restrict__ sorted_src, const int* __restrict__ row_start,
    float* __restrict__ alpha_sorted, float* __restrict__ slots, int N)
{
    const int t = threadIdx.x;
    const int wid = t >> 6, lane = t & 63;
    const int g = lane >> 3;       // edge group 0..7
    const int c8 = lane & 7;       // channel octet
    const int node = blockIdx.x * 4 + wid;
    float lsum = 0.f, lsq = 0.f;
    if (node < N) {
        const uint4 qw = reinterpret_cast<const uint4*>(q + (size_t)node * D_OUT)[c8];
        const int s0 = row_start[node], s1 = row_start[node + 1];
        for (int j0 = s0; j0 < s1; j0 += 32) {
            const int nb = min(s1 - j0, 32);
            int sv = 0;
            if (lane < nb) sv = sorted_src[j0 + lane];
            uint4 kw[4];
#pragma unroll
            for (int it = 0; it < 4; ++it) {
                int sidx = __shfl(sv, it * 8 + g, 64);
                kw[it] = make_uint4(0u, 0u, 0u, 0u);
                if (it * 8 + g < nb)
                    kw[it] = reinterpret_cast<const uint4*>(k + (size_t)sidx * D_OUT)[c8];
            }
#pragma unroll
            for (int it = 0; it < 4; ++it) {
                const bool valid = it * 8 + g < nb;
                float p = dot2bf(qw.x, kw[it].x, 0.f);
                p = dot2bf(qw.y, kw[it].y, p);
                p = dot2bf(qw.z, kw[it].z, p);
                p = dot2bf(qw.w, kw[it].w, p);
                p += __shfl_xor(p, 1, 8);
                p += __shfl_xor(p, 2, 8);
                p += __shfl_xor(p, 4, 8);
                if (valid && c8 == 0) {
                    float a = p * 0.125f;   // 1/sqrt(64)
                    alpha_sorted[j0 + it * 8 + g] = a;
                    lsum += a;
                    lsq += a * a;
                }
            }
        }
    }
#pragma unroll
    for (int off = 1; off < 64; off <<= 1) {
        lsum += __shfl_xor(lsum, off, 64);
        lsq  += __shfl_xor(lsq,  off, 64);
    }
    __shared__ float red[2][4];
    if (lane == 0) { red[0][wid] = lsum; red[1][wid] = lsq; }
    __syncthreads();
    if (t == 0) {
        float* sl = slots + (blockIdx.x & (NSLOT - 1)) * SLOT_STRIDE;
        atomicAdd(&sl[0], red[0][0] + red[0][1] + red[0][2] + red[0][3]);
        atomicAdd(&sl[1], red[1][0] + red[1][1] + red[1][2] + red[1][3]);
    }
}

// ---------------- finalize mean/std (reduce 64 slots) ----------------
__global__ void finalize_stats_kernel(const float* __restrict__ slots,
                                      float* stats, int E) {
    const int lane = threadIdx.x & 63;
    float s  = slots[lane * SLOT_STRIDE];
    float s2 = slots[lane * SLOT_STRIDE + 1];
#pragma unroll
    for (int off = 1; off < 64; off <<= 1) {
        s  += __shfl_xor(s,  off, 64);
        s2 += __shfl_xor(s2, off, 64);
    }
    if (lane == 0) {
        float mean = s / (float)E;
        float var = (s2 - (float)E * mean * mean) / (float)(E - 1);
        stats[2] = mean;
        stats[3] = SCALE_PARAM / sqrtf(var);
    }
}

// ---------------- per-node accumulate: 4-deep v-gather ILP ------------
__global__ __launch_bounds__(256) void node_gather_kernel(
    const ushortt* __restrict__ v, const int* __restrict__ sorted_src,
    const float* __restrict__ alpha_sorted, const int* __restrict__ row_start,
    const float* __restrict__ stats, float* __restrict__ out, int N)
{
    const int t = threadIdx.x;
    const int wid = t >> 6, lane = t & 63;
    const int g = lane >> 3, c8 = lane & 7;
    const int node = blockIdx.x * 4 + wid;
    if (node >= N) return;
    const float mean = stats[2], coef = stats[3];
    float a0 = 0, a1 = 0, a2 = 0, a3 = 0, a4 = 0, a5 = 0, a6 = 0, a7 = 0;
    const int s0 = row_start[node], s1 = row_start[node + 1];
    for (int j0 = s0; j0 < s1; j0 += 32) {
        const int nb = min(s1 - j0, 32);
        int sv = 0;
        float av = 0.f;
        if (lane < nb) {
            sv = sorted_src[j0 + lane];
            float al = alpha_sorted[j0 + lane];
            al = (al - mean) * coef;
            av = 1.f / (1.f + __expf(-al));
        }
        uint4 vw[4];
        float alv[4];
#pragma unroll
        for (int it = 0; it < 4; ++it) {
            int sidx = __shfl(sv, it * 8 + g, 64);
            alv[it] = __shfl(av, it * 8 + g, 64);
            vw[it] = make_uint4(0u, 0u, 0u, 0u);
            if (it * 8 + g < nb)
                vw[it] = reinterpret_cast<const uint4*>(v + (size_t)sidx * D_OUT)[c8];
        }
#pragma unroll
        for (int it = 0; it < 4; ++it) {
            const float al = (it * 8 + g < nb) ? alv[it] : 0.f;
            a0 = fmaf(bflo(vw[it].x), al, a0); a1 = fmaf(bfhi(vw[it].x), al, a1);
            a2 = fmaf(bflo(vw[it].y), al, a2); a3 = fmaf(bfhi(vw[it].y), al, a3);
            a4 = fmaf(bflo(vw[it].z), al, a4); a5 = fmaf(bfhi(vw[it].z), al, a5);
            a6 = fmaf(bflo(vw[it].w), al, a6); a7 = fmaf(bfhi(vw[it].w), al, a7);
        }
    }
#pragma unroll
    for (int off = 8; off < 64; off <<= 1) {
        a0 += __shfl_xor(a0, off, 64); a1 += __shfl_xor(a1, off, 64);
        a2 += __shfl_xor(a2, off, 64); a3 += __shfl_xor(a3, off, 64);
        a4 += __shfl_xor(a4, off, 64); a5 += __shfl_xor(a5, off, 64);
        a6 += __shfl_xor(a6, off, 64); a7 += __shfl_xor(a7, off, 64);
    }
    if (g == 0) {
        float* op = out + (size_t)node * D_OUT + c8 * 8;
        float4 c0 = *reinterpret_cast<float4*>(op);
        float4 c1 = *reinterpret_cast<float4*>(op + 4);
        c0.x += a0; c0.y += a1; c0.z += a2; c0.w += a3;
        c1.x += a4; c1.y += a5; c1.z += a6; c1.w += a7;
        *reinterpret_cast<float4*>(op)     = c0;
        *reinterpret_cast<float4*>(op + 4) = c1;
    }
}

extern "C" void kernel_launch(void* const* d_in, const int* in_sizes, int n_in,
                              void* d_out, int out_size, void* d_ws, size_t ws_size,
                              hipStream_t stream) {
    const float* x     = (const float*)d_in[0];
    const int*   eidx  = (const int*)d_in[1];
    const float* Wq    = (const float*)d_in[2];
    const float* bq    = (const float*)d_in[3];
    const float* Wk    = (const float*)d_in[4];
    const float* bk    = (const float*)d_in[5];
    const float* Wv    = (const float*)d_in[6];
    const float* bv    = (const float*)d_in[7];
    const float* Ws    = (const float*)d_in[8];
    const float* bs    = (const float*)d_in[9];
    float* out = (float*)d_out;

    const int N = in_sizes[0] / D_IN;
    const int E = in_sizes[1] / 2;
    const int* src = eidx;
    const int* dst = eidx + E;
    const int NBUCK = (N + NPB - 1) >> NPB_LOG;   // 196

    char* base = (char*)d_ws;
    size_t cur = 0;
    auto carve = [&](size_t bytes) -> char* {
        char* p = base + cur;
        cur = (cur + bytes + 255) & ~(size_t)255;
        return p;
    };
    const size_t nodebf = (size_t)N * D_OUT * sizeof(ushortt);
    ushortt* q          = (ushortt*)carve(nodebf);
    ushortt* k          = (ushortt*)carve(nodebf);
    ushortt* v          = (ushortt*)carve(nodebf);
    float* alpha_sorted = (float*)carve((size_t)E * sizeof(float));
    int*   sorted_src   = (int*)carve((size_t)E * sizeof(int));
    unsigned* ebuf      = (unsigned*)carve((size_t)E * sizeof(unsigned));
    uint4* wfrag        = (uint4*)carve(4096 * sizeof(uint4));   // 64 KB
    const size_t ccnt_b  = (MAXBUCK * sizeof(int) + 255) & ~(size_t)255;
    const size_t slots_b = (size_t)NSLOT * SLOT_STRIDE * sizeof(float);
    char*  zreg         = carve(ccnt_b + slots_b + 256);
    int*   ccnt         = (int*)zreg;
    float* slots        = (float*)(zreg + ccnt_b);
    float* stats        = (float*)(zreg + ccnt_b + slots_b);
    int*   row_start    = (int*)carve((size_t)(N + 1) * sizeof(int));
    int*   bb           = (int*)carve((size_t)(MAXBUCK + 1) * sizeof(int));
    int*   tails        = (int*)carve((size_t)MAXBUCK * sizeof(int));

    hipMemsetAsync(zreg, 0, ccnt_b + slots_b + 256, stream);

    // fused: prep_w (16 blocks) + coarse hist (512 blocks)
    prep_hist_kernel<<<PREP_BLKS + 512, 256, 0, stream>>>(
        Wq, Wk, Wv, Ws, wfrag, dst, ccnt, E);
    coarse_scan_kernel<<<1, 64, 0, stream>>>(ccnt, bb, tails, NBUCK);

    // fused: multisplit (512 blocks) + GEMM (1563 blocks)
    const int gemm_grid = (N + 63) / 64;
    gemm_ms_kernel<<<MSF_NBLK + gemm_grid, 256, 0, stream>>>(
        x, wfrag, bq, bk, bv, bs, q, k, v, out, N,
        src, dst, tails, ebuf, E);

    fine_sort_kernel<<<NBUCK, 512, 0, stream>>>(
        ebuf, bb, sorted_src, row_start, N, NBUCK);

    node_logit_kernel<<<(N + 3) / 4, 256, 0, stream>>>(
        q, k, sorted_src, row_start, alpha_sorted, slots, N);
    finalize_stats_kernel<<<1, 64, 0, stream>>>(slots, stats, E);
    node_gather_kernel<<<(N + 3) / 4, 256, 0, stream>>>(
        v, sorted_src, alpha_sorted, row_start, stats, out, N);
}

// Round 21
// 175.639 us; speedup vs baseline: 1.0121x; 1.0121x over previous
//
#include <hip/hip_runtime.h>
#include <math.h>

#define D_IN 128
#define D_OUT 64
#define SCALE_PARAM 2.0f
#define NSLOT 64          // spread slots for stats atomics (64B-line spaced)
#define SLOT_STRIDE 16    // floats
#define NPB_LOG 9         // 512 nodes per coarse bucket (pow2)
#define NPB 512
#define MAXBUCK 256       // >= NBUCK = ceil(N/512) = 196
#define MSF_NBLK 512      // multisplit blocks (fused, 256 threads each)
#define PREP_BLKS 16      // prep_w blocks in fused prep+hist kernel
#define GEMM_TPB 2        // tiles per GEMM block (grid stays >= 3 waves/SIMD)

typedef unsigned short ushortt;
typedef __attribute__((ext_vector_type(8))) short bf16x8;
typedef __attribute__((ext_vector_type(4))) float f32x4;

__device__ __forceinline__ ushortt f2bf(float f) {
    union { float f; unsigned u; } cv; cv.f = f;
    unsigned u = cv.u;
    return (ushortt)((u + 0x7FFFu + ((u >> 16) & 1u)) >> 16);
}
__device__ __forceinline__ unsigned cvt_pk_bf16(float a, float b) {
    unsigned r;
    asm("v_cvt_pk_bf16_f32 %0, %1, %2" : "=v"(r) : "v"(a), "v"(b));
    return r;
}
// packed bf16 dot2 with f32 accumulate: d = a.lo*b.lo + a.hi*b.hi + c
__device__ __forceinline__ float dot2bf(unsigned a, unsigned b, float c) {
    float d;
    asm("v_dot2_f32_bf16 %0, %1, %2, %3" : "=v"(d) : "v"(a), "v"(b), "v"(c));
    return d;
}
__device__ __forceinline__ float bflo(unsigned w) {
    union { unsigned u; float f; } cv; cv.u = w << 16;
    return cv.f;
}
__device__ __forceinline__ float bfhi(unsigned w) {
    union { unsigned u; float f; } cv; cv.u = w & 0xFFFF0000u;
    return cv.f;
}

// ---------------- fused: W fragment pre-pack + dst coarse histogram ----
__global__ __launch_bounds__(256) void prep_hist_kernel(
    const float* __restrict__ Wq, const float* __restrict__ Wk,
    const float* __restrict__ Wv, const float* __restrict__ Ws,
    uint4* __restrict__ wfrag,
    const int* __restrict__ dst, int* __restrict__ ccnt, int E)
{
    __shared__ int lc[MAXBUCK];
    const int t = threadIdx.x;
    if (blockIdx.x < PREP_BLKS) {
        const int gid = blockIdx.x * 256 + t;   // 0..4095
        const int l  = gid & 63;
        const int ci = (gid >> 6) & 3;
        const int ks = (gid >> 8) & 3;
        const int m  = (gid >> 10) & 3;
        const float* Wm = (m == 0) ? Wq : (m == 1) ? Wk : (m == 2) ? Wv : Ws;
        const int cl = l & 15;
        const int kb8 = (l >> 4) * 8;
        unsigned pk[4];
#pragma unroll
        for (int p = 0; p < 4; ++p) {
            float f0 = Wm[(ks * 32 + kb8 + 2 * p)     * D_OUT + ci * 16 + cl];
            float f1 = Wm[(ks * 32 + kb8 + 2 * p + 1) * D_OUT + ci * 16 + cl];
            pk[p] = (unsigned)f2bf(f0) | ((unsigned)f2bf(f1) << 16);
        }
        wfrag[gid] = make_uint4(pk[0], pk[1], pk[2], pk[3]);
    } else {
        const int blk = blockIdx.x - PREP_BLKS;       // 0..511
        const int nblk = gridDim.x - PREP_BLKS;       // 512
        if (t < MAXBUCK) lc[t] = 0;
        __syncthreads();
        const int stride = nblk * 256 * 4;
        for (int base = (blk * 256 + t) * 4; base < E; base += stride) {
            if (base + 3 < E) {
                int4 d = *reinterpret_cast<const int4*>(&dst[base]);
                atomicAdd(&lc[d.x >> NPB_LOG], 1);
                atomicAdd(&lc[d.y >> NPB_LOG], 1);
                atomicAdd(&lc[d.z >> NPB_LOG], 1);
                atomicAdd(&lc[d.w >> NPB_LOG], 1);
            } else {
                for (int i = base; i < E; ++i) atomicAdd(&lc[dst[i] >> NPB_LOG], 1);
            }
        }
        __syncthreads();
        if (t < MAXBUCK && lc[t]) atomicAdd(&ccnt[t], lc[t]);
    }
}

// ---------------- coarse scan (tiny) ----------------
__global__ void coarse_scan_kernel(const int* __restrict__ ccnt,
                                   int* __restrict__ bb, int* __restrict__ tails,
                                   int NBUCK)
{
    if (threadIdx.x == 0) {
        int run = 0;
        for (int b = 0; b < NBUCK; ++b) {
            bb[b] = run;
            tails[b] = run;
            run += ccnt[b];
        }
        bb[NBUCK] = run;   // = E
    }
}

// ---------------- fused: multisplit (blocks 0..511) + MFMA GEMM -------
// GEMM blocks each handle GEMM_TPB tiles: W fragments loaded once/block.
__global__ __launch_bounds__(256) void gemm_ms_kernel(
    const float* __restrict__ x, const uint4* __restrict__ wfrag,
    const float* __restrict__ bq, const float* __restrict__ bk,
    const float* __restrict__ bv, const float* __restrict__ bs,
    ushortt* __restrict__ q, ushortt* __restrict__ kk, ushortt* __restrict__ v,
    float* __restrict__ skip, int N, int ntiles,
    const int* __restrict__ src, const int* __restrict__ dst,
    int* __restrict__ tails, unsigned* __restrict__ ebuf, int E)
{
    __shared__ __align__(16) char smem[64 * 128 * 2];   // 16 KB shared pool
    const int t = threadIdx.x;

    if (blockIdx.x < MSF_NBLK) {
        // ================= multisplit =================
        int* cnt    = (int*)smem;                 // [MAXBUCK]
        int* curc   = (int*)(smem + 1024);        // [MAXBUCK]
        int* base_l = (int*)(smem + 2048);        // [MAXBUCK]
        const int blk = blockIdx.x;
        const int e0 = (int)((long long)blk * E / MSF_NBLK);
        const int e1 = (int)((long long)(blk + 1) * E / MSF_NBLK);
        if (t < MAXBUCK) { cnt[t] = 0; curc[t] = 0; }
        __syncthreads();
        for (int e = e0 + t; e < e1; e += 256)
            atomicAdd(&cnt[dst[e] >> NPB_LOG], 1);
        __syncthreads();
        if (t < MAXBUCK) {
            int c = cnt[t];
            base_l[t] = c ? atomicAdd(&tails[t], c) : 0;
        }
        __syncthreads();
        for (int e = e0 + t; e < e1; e += 256) {
            int d = dst[e];
            int b = d >> NPB_LOG;
            int r = atomicAdd(&curc[b], 1);
            ebuf[base_l[b] + r] = ((unsigned)(d & (NPB - 1)) << 17) | (unsigned)src[e];
        }
        return;
    }

    // ================= GEMM =================
    char* AsB = smem;
    const int w = t >> 6;          // wave id = matrix id
    const int l = t & 63;
    const int cl = l & 15;
    const int kb8 = (l >> 4) * 8;
    const int rbase = (l >> 4) * 4;

    const float* bp = (w == 0) ? bq : (w == 1) ? bk : (w == 2) ? bv : bs;

    // W fragments + bias: loaded ONCE per block (amortized over GEMM_TPB tiles)
    union U8 { uint4 u; bf16x8 v; };
    bf16x8 bfr[4][4];
#pragma unroll
    for (int ks = 0; ks < 4; ++ks)
#pragma unroll
        for (int ci = 0; ci < 4; ++ci) {
            U8 tmp; tmp.u = wfrag[((w * 4 + ks) * 4 + ci) * 64 + l];
            bfr[ks][ci] = tmp.v;
        }
    float4 bias4[4];
#pragma unroll
    for (int ci = 0; ci < 4; ++ci)
        bias4[ci] = reinterpret_cast<const float4*>(bp)[ci * 4 + (l >> 4)];

    ushortt* qkv = (w == 0) ? q : (w == 1) ? kk : v;
    const int tile0 = (blockIdx.x - MSF_NBLK) * GEMM_TPB;
    const int tile1 = min(tile0 + GEMM_TPB, ntiles);

    for (int tile = tile0; tile < tile1; ++tile) {
        const int row0 = tile * 64;

        // phase 1: issue ALL x loads
        float4 xv[8];
#pragma unroll
        for (int i = 0; i < 8; ++i) {
            int f = i * 256 + t;
            int r = f >> 5;
            int k4 = f & 31;
            int grow = row0 + r;
            xv[i] = make_float4(0.f, 0.f, 0.f, 0.f);
            if (grow < N)
                xv[i] = *reinterpret_cast<const float4*>(&x[(size_t)grow * D_IN + k4 * 4]);
        }

        // phase 2: cvt + LDS writes
#pragma unroll
        for (int i = 0; i < 8; ++i) {
            int f = i * 256 + t;
            int r = f >> 5;
            int k4 = f & 31;
            uint2 pk;
            pk.x = cvt_pk_bf16(xv[i].x, xv[i].y);
            pk.y = cvt_pk_bf16(xv[i].z, xv[i].w);
            int addr = r * 256 + ((k4 * 8) ^ ((r & 7) << 4));
            *reinterpret_cast<uint2*>(AsB + addr) = pk;
        }
        __syncthreads();

        f32x4 acc[4][4];
#pragma unroll
        for (int ri = 0; ri < 4; ++ri)
#pragma unroll
            for (int ci = 0; ci < 4; ++ci) acc[ri][ci] = (f32x4)(0.f);

#pragma unroll
        for (int ks = 0; ks < 4; ++ks) {
            bf16x8 afr[4];
#pragma unroll
            for (int ri = 0; ri < 4; ++ri) {
                int row = ri * 16 + cl;
                int kby = ks * 64 + kb8 * 2;
                int addr = row * 256 + (kby ^ ((row & 7) << 4));
                afr[ri] = *reinterpret_cast<const bf16x8*>(AsB + addr);
            }
            // swapped operands -> transposed output fragments
#pragma unroll
            for (int ri = 0; ri < 4; ++ri)
#pragma unroll
                for (int ci = 0; ci < 4; ++ci)
                    acc[ri][ci] = __builtin_amdgcn_mfma_f32_16x16x32_bf16(
                        bfr[ks][ci], afr[ri], acc[ri][ci], 0, 0, 0);
        }

        // epilogue: lane holds row=ri*16+cl, cols=ci*16+rbase+0..3
#pragma unroll
        for (int ri = 0; ri < 4; ++ri) {
            int grow = row0 + ri * 16 + cl;
            if (grow >= N) continue;
            if (w == 3) {
#pragma unroll
                for (int ci = 0; ci < 4; ++ci) {
                    float4 o;
                    o.x = acc[ri][ci][0] + bias4[ci].x;
                    o.y = acc[ri][ci][1] + bias4[ci].y;
                    o.z = acc[ri][ci][2] + bias4[ci].z;
                    o.w = acc[ri][ci][3] + bias4[ci].w;
                    *reinterpret_cast<float4*>(&skip[(size_t)grow * D_OUT + ci * 16 + rbase]) = o;
                }
            } else {
#pragma unroll
                for (int ci = 0; ci < 4; ++ci) {
                    uint2 pk;
                    pk.x = cvt_pk_bf16(acc[ri][ci][0] + bias4[ci].x,
                                       acc[ri][ci][1] + bias4[ci].y);
                    pk.y = cvt_pk_bf16(acc[ri][ci][2] + bias4[ci].z,
                                       acc[ri][ci][3] + bias4[ci].w);
                    *reinterpret_cast<uint2*>(&qkv[(size_t)grow * D_OUT + ci * 16 + rbase]) = pk;
                }
            }
        }
        __syncthreads();   // LDS reuse barrier before next tile's stage
    }
}

// ---------------- fine sort within coarse bucket ----------------
__global__ __launch_bounds__(512) void fine_sort_kernel(
    const unsigned* __restrict__ ebuf, const int* __restrict__ bb,
    int* __restrict__ sorted_src, int* __restrict__ row_start,
    int N, int NBUCK)
{
    __shared__ int cnt[NPB];
    __shared__ int cur[NPB];
    __shared__ int wsum[8];
    const int t = threadIdx.x;
    const int b = blockIdx.x;
    const int nbase = b << NPB_LOG;
    const int seg0 = bb[b], seg1 = bb[b + 1];

    cnt[t] = 0; cur[t] = 0;
    __syncthreads();
    for (int j = seg0 + t; j < seg1; j += 512)
        atomicAdd(&cnt[ebuf[j] >> 17], 1);
    __syncthreads();

    {
        const int lane = t & 63, wid = t >> 6;
        int c = cnt[t];
        int x = c;
#pragma unroll
        for (int off = 1; off < 64; off <<= 1) {
            int n = __shfl_up(x, off, 64);
            if (lane >= off) x += n;
        }
        if (lane == 63) wsum[wid] = x;
        __syncthreads();
        int woff = 0;
        for (int w = 0; w < wid; ++w) woff += wsum[w];
        int excl = x - c + woff;
        cnt[t] = excl;
        int node = nbase + t;
        if (node < N) row_start[node] = seg0 + excl;
    }
    if (b == NBUCK - 1 && t == 0) row_start[N] = seg1;
    __syncthreads();

    for (int j = seg0 + t; j < seg1; j += 512) {
        unsigned u = ebuf[j];
        int dl = u >> 17;
        int r = atomicAdd(&cur[dl], 1);
        sorted_src[seg0 + cnt[dl] + r] = (int)(u & 0x1FFFFu);
    }
}

// ---------------- per-node logits + stats: dot2 + 4-deep gather ILP ---
__global__ __launch_bounds__(256) void node_logit_kernel(
    const ushortt* __restrict__ q, const ushortt* __restrict__ k,
    const int* __restrict__ sorted_src, const int* __restrict__ row_start,
    float* __restrict__ alpha_sorted, float* __restrict__ slots, int N)
{
    const int t = threadIdx.x;
    const int wid = t >> 6, lane = t & 63;
    const int g = lane >> 3;       // edge group 0..7
    const int c8 = lane & 7;       // channel octet
    const int node = blockIdx.x * 4 + wid;
    float lsum = 0.f, lsq = 0.f;
    if (node < N) {
        const uint4 qw = reinterpret_cast<const uint4*>(q + (size_t)node * D_OUT)[c8];
        const int s0 = row_start[node], s1 = row_start[node + 1];
        for (int j0 = s0; j0 < s1; j0 += 32) {
            const int nb = min(s1 - j0, 32);
            int sv = 0;
            if (lane < nb) sv = sorted_src[j0 + lane];
            uint4 kw[4];
#pragma unroll
            for (int it = 0; it < 4; ++it) {
                int sidx = __shfl(sv, it * 8 + g, 64);
                kw[it] = make_uint4(0u, 0u, 0u, 0u);
                if (it * 8 + g < nb)
                    kw[it] = reinterpret_cast<const uint4*>(k + (size_t)sidx * D_OUT)[c8];
            }
#pragma unroll
            for (int it = 0; it < 4; ++it) {
                const bool valid = it * 8 + g < nb;
                float p = dot2bf(qw.x, kw[it].x, 0.f);
                p = dot2bf(qw.y, kw[it].y, p);
                p = dot2bf(qw.z, kw[it].z, p);
                p = dot2bf(qw.w, kw[it].w, p);
                p += __shfl_xor(p, 1, 8);
                p += __shfl_xor(p, 2, 8);
                p += __shfl_xor(p, 4, 8);
                if (valid && c8 == 0) {
                    float a = p * 0.125f;   // 1/sqrt(64)
                    alpha_sorted[j0 + it * 8 + g] = a;
                    lsum += a;
                    lsq += a * a;
                }
            }
        }
    }
#pragma unroll
    for (int off = 1; off < 64; off <<= 1) {
        lsum += __shfl_xor(lsum, off, 64);
        lsq  += __shfl_xor(lsq,  off, 64);
    }
    __shared__ float red[2][4];
    if (lane == 0) { red[0][wid] = lsum; red[1][wid] = lsq; }
    __syncthreads();
    if (t == 0) {
        float* sl = slots + (blockIdx.x & (NSLOT - 1)) * SLOT_STRIDE;
        atomicAdd(&sl[0], red[0][0] + red[0][1] + red[0][2] + red[0][3]);
        atomicAdd(&sl[1], red[1][0] + red[1][1] + red[1][2] + red[1][3]);
    }
}

// ---------------- finalize mean/std (reduce 64 slots) ----------------
__global__ void finalize_stats_kernel(const float* __restrict__ slots,
                                      float* stats, int E) {
    const int lane = threadIdx.x & 63;
    float s  = slots[lane * SLOT_STRIDE];
    float s2 = slots[lane * SLOT_STRIDE + 1];
#pragma unroll
    for (int off = 1; off < 64; off <<= 1) {
        s  += __shfl_xor(s,  off, 64);
        s2 += __shfl_xor(s2, off, 64);
    }
    if (lane == 0) {
        float mean = s / (float)E;
        float var = (s2 - (float)E * mean * mean) / (float)(E - 1);
        stats[2] = mean;
        stats[3] = SCALE_PARAM / sqrtf(var);
    }
}

// ---------------- per-node accumulate: 4-deep v-gather ILP ------------
__global__ __launch_bounds__(256) void node_gather_kernel(
    const ushortt* __restrict__ v, const int* __restrict__ sorted_src,
    const float* __restrict__ alpha_sorted, const int* __restrict__ row_start,
    const float* __restrict__ stats, float* __restrict__ out, int N)
{
    const int t = threadIdx.x;
    const int wid = t >> 6, lane = t & 63;
    const int g = lane >> 3, c8 = lane & 7;
    const int node = blockIdx.x * 4 + wid;
    if (node >= N) return;
    const float mean = stats[2], coef = stats[3];
    float a0 = 0, a1 = 0, a2 = 0, a3 = 0, a4 = 0, a5 = 0, a6 = 0, a7 = 0;
    const int s0 = row_start[node], s1 = row_start[node + 1];
    for (int j0 = s0; j0 < s1; j0 += 32) {
        const int nb = min(s1 - j0, 32);
        int sv = 0;
        float av = 0.f;
        if (lane < nb) {
            sv = sorted_src[j0 + lane];
            float al = alpha_sorted[j0 + lane];
            al = (al - mean) * coef;
            av = 1.f / (1.f + __expf(-al));
        }
        uint4 vw[4];
        float alv[4];
#pragma unroll
        for (int it = 0; it < 4; ++it) {
            int sidx = __shfl(sv, it * 8 + g, 64);
            alv[it] = __shfl(av, it * 8 + g, 64);
            vw[it] = make_uint4(0u, 0u, 0u, 0u);
            if (it * 8 + g < nb)
                vw[it] = reinterpret_cast<const uint4*>(v + (size_t)sidx * D_OUT)[c8];
        }
#pragma unroll
        for (int it = 0; it < 4; ++it) {
            const float al = (it * 8 + g < nb) ? alv[it] : 0.f;
            a0 = fmaf(bflo(vw[it].x), al, a0); a1 = fmaf(bfhi(vw[it].x), al, a1);
            a2 = fmaf(bflo(vw[it].y), al, a2); a3 = fmaf(bfhi(vw[it].y), al, a3);
            a4 = fmaf(bflo(vw[it].z), al, a4); a5 = fmaf(bfhi(vw[it].z), al, a5);
            a6 = fmaf(bflo(vw[it].w), al, a6); a7 = fmaf(bfhi(vw[it].w), al, a7);
        }
    }
#pragma unroll
    for (int off = 8; off < 64; off <<= 1) {
        a0 += __shfl_xor(a0, off, 64); a1 += __shfl_xor(a1, off, 64);
        a2 += __shfl_xor(a2, off, 64); a3 += __shfl_xor(a3, off, 64);
        a4 += __shfl_xor(a4, off, 64); a5 += __shfl_xor(a5, off, 64);
        a6 += __shfl_xor(a6, off, 64); a7 += __shfl_xor(a7, off, 64);
    }
    if (g == 0) {
        float* op = out + (size_t)node * D_OUT + c8 * 8;
        float4 c0 = *reinterpret_cast<float4*>(op);
        float4 c1 = *reinterpret_cast<float4*>(op + 4);
        c0.x += a0; c0.y += a1; c0.z += a2; c0.w += a3;
        c1.x += a4; c1.y += a5; c1.z += a6; c1.w += a7;
        *reinterpret_cast<float4*>(op)     = c0;
        *reinterpret_cast<float4*>(op + 4) = c1;
    }
}

extern "C" void kernel_launch(void* const* d_in, const int* in_sizes, int n_in,
                              void* d_out, int out_size, void* d_ws, size_t ws_size,
                              hipStream_t stream) {
    const float* x     = (const float*)d_in[0];
    const int*   eidx  = (const int*)d_in[1];
    const float* Wq    = (const float*)d_in[2];
    const float* bq    = (const float*)d_in[3];
    const float* Wk    = (const float*)d_in[4];
    const float* bk    = (const float*)d_in[5];
    const float* Wv    = (const float*)d_in[6];
    const float* bv    = (const float*)d_in[7];
    const float* Ws    = (const float*)d_in[8];
    const float* bs    = (const float*)d_in[9];
    float* out = (float*)d_out;

    const int N = in_sizes[0] / D_IN;
    const int E = in_sizes[1] / 2;
    const int* src = eidx;
    const int* dst = eidx + E;
    const int NBUCK = (N + NPB - 1) >> NPB_LOG;   // 196

    char* base = (char*)d_ws;
    size_t cur = 0;
    auto carve = [&](size_t bytes) -> char* {
        char* p = base + cur;
        cur = (cur + bytes + 255) & ~(size_t)255;
        return p;
    };
    const size_t nodebf = (size_t)N * D_OUT * sizeof(ushortt);
    ushortt* q          = (ushortt*)carve(nodebf);
    ushortt* k          = (ushortt*)carve(nodebf);
    ushortt* v          = (ushortt*)carve(nodebf);
    float* alpha_sorted = (float*)carve((size_t)E * sizeof(float));
    int*   sorted_src   = (int*)carve((size_t)E * sizeof(int));
    unsigned* ebuf      = (unsigned*)carve((size_t)E * sizeof(unsigned));
    uint4* wfrag        = (uint4*)carve(4096 * sizeof(uint4));   // 64 KB
    const size_t ccnt_b  = (MAXBUCK * sizeof(int) + 255) & ~(size_t)255;
    const size_t slots_b = (size_t)NSLOT * SLOT_STRIDE * sizeof(float);
    char*  zreg         = carve(ccnt_b + slots_b + 256);
    int*   ccnt         = (int*)zreg;
    float* slots        = (float*)(zreg + ccnt_b);
    float* stats        = (float*)(zreg + ccnt_b + slots_b);
    int*   row_start    = (int*)carve((size_t)(N + 1) * sizeof(int));
    int*   bb           = (int*)carve((size_t)(MAXBUCK + 1) * sizeof(int));
    int*   tails        = (int*)carve((size_t)MAXBUCK * sizeof(int));

    hipMemsetAsync(zreg, 0, ccnt_b + slots_b + 256, stream);

    // fused: prep_w (16 blocks) + coarse hist (512 blocks)
    prep_hist_kernel<<<PREP_BLKS + 512, 256, 0, stream>>>(
        Wq, Wk, Wv, Ws, wfrag, dst, ccnt, E);
    coarse_scan_kernel<<<1, 64, 0, stream>>>(ccnt, bb, tails, NBUCK);

    // fused: multisplit (512 blocks) + GEMM (782 blocks x 2 tiles)
    const int ntiles = (N + 63) / 64;
    const int gemm_grid = (ntiles + GEMM_TPB - 1) / GEMM_TPB;
    gemm_ms_kernel<<<MSF_NBLK + gemm_grid, 256, 0, stream>>>(
        x, wfrag, bq, bk, bv, bs, q, k, v, out, N, ntiles,
        src, dst, tails, ebuf, E);

    fine_sort_kernel<<<NBUCK, 512, 0, stream>>>(
        ebuf, bb, sorted_src, row_start, N, NBUCK);

    node_logit_kernel<<<(N + 3) / 4, 256, 0, stream>>>(
        q, k, sorted_src, row_start, alpha_sorted, slots, N);
    finalize_stats_kernel<<<1, 64, 0, stream>>>(slots, stats, E);
    node_gather_kernel<<<(N + 3) / 4, 256, 0, stream>>>(
        v, sorted_src, alpha_sorted, row_start, stats, out, N);
}